// Round 1
// baseline (419.499 us; speedup 1.0000x reference)
//
#include <hip/hip_runtime.h>
#include <math.h>

// Problem constants (from reference)
#define K_SHEET   0.01f
#define K_CHAN    0.1f
#define CAV_SPACE 2.0f
#define FLOW_EXP  1.25f

// DISS = (1/917 - 1/1000)/3.34e5, computed in double, used as f32 (matches jnp cast)
__device__ __constant__ float c_diss = (float)((1.0 / 917.0 - 1.0 / 1000.0) / 3.34e5);

// One block per matrix row. Threads 0..3 compute the per-slot terms (identical
// arithmetic + accumulation order to the verified patch kernel -> bit-identical
// output). Then all 256 threads stream the row as float4 zeros, substituting the
// <=5 nonzeros inline. The whole 400 MB output is written exactly once; no
// memset pass, no scattered write-allocate RMW.
__global__ __launch_bounds__(256)
void sgds_row_kernel(const float* __restrict__ pot,          // [N]
                     const float* __restrict__ chan,         // [L]
                     const float* __restrict__ sheet,        // [N]
                     const float* __restrict__ face_len,     // [L]
                     const float* __restrict__ link_len,     // [L]
                     const int*   __restrict__ adj,          // [N,4]
                     const int*   __restrict__ lnk,          // [N,4]
                     const int*   __restrict__ fal,          // [L]
                     const int*   __restrict__ head,         // [L]
                     const int*   __restrict__ tail,         // [L]
                     const int*   __restrict__ inout,        // [N]
                     float*       __restrict__ M,            // [N,N]
                     int N)
{
    const int i   = blockIdx.x;        // row id (uniform)
    const int tid = threadIdx.x;

    __shared__ float s_term[4];
    __shared__ int   s_col[4];

    const bool dirichlet = (inout[i] == 1);

    if (!dirichlet && tid < 4) {
        const int s = tid;
        int j = adj[i * 4 + s];
        if (j < 0) {
            s_col[s] = -1;
        } else {
            int   lid = lnk[i * 4 + s];
            int   h   = head[lid];
            int   t   = tail[lid];
            float ll  = link_len[lid];
            float g   = (pot[h] - pot[t]) / ll;                 // grad[lid]

            float cq  = -K_CHAN * powf(chan[lid], FLOW_EXP) * g;          // chan_q
            float stl = 0.5f * (sheet[h] + sheet[t]);
            float ginv_sqrt = 1.0f / sqrtf(fabsf(g));                      // |g|^-0.5
            float sq  = -K_SHEET * powf(stl, FLOW_EXP) * ginv_sqrt * g;    // sheet_q

            float fl = face_len[fal[lid]];
            // NOTE: reference indexes channel_size (link field) by NODE ids — kept.
            float cs = 0.5f * (chan[i] + chan[j]);
            float st = 0.5f * (sheet[i] + sheet[j]);

            float sheet_flux = -K_SHEET * powf(st, FLOW_EXP) * ginv_sqrt * fl / ll;
            float chan_flux  = -K_CHAN  * powf(cs, FLOW_EXP) * fl / ll;
            float ch_diss    = fabsf(c_diss * cq * fl);
            float sh_diss    = fabsf(c_diss * sq * CAV_SPACE * fl);

            s_term[s] = sheet_flux + chan_flux + ch_diss + sh_diss;
            s_col[s]  = j;
        }
    }
    __syncthreads();

    // Build the row's patch list in NAMED registers (no runtime-indexed arrays).
    int   c0 = -1, c1 = -1, c2 = -1, c3 = -1;
    float v0 = 0.f, v1 = 0.f, v2 = 0.f, v3 = 0.f;
    float v4;
    const int c4 = i;                       // diagonal column (always present)

    if (dirichlet) {
        v4 = 1.0f;                          // identity row
    } else {
        float diag = 0.0f;                  // same accumulation order as before: s=0..3
        if (s_col[0] >= 0) { c0 = s_col[0]; float t = s_term[0]; v0 = -t; diag += t; }
        if (s_col[1] >= 0) { c1 = s_col[1]; float t = s_term[1]; v1 = -t; diag += t; }
        if (s_col[2] >= 0) { c2 = s_col[2]; float t = s_term[2]; v2 = -t; diag += t; }
        if (s_col[3] >= 0) { c3 = s_col[3]; float t = s_term[3]; v3 = -t; diag += t; }
        v4 = diag;
    }

    // Band of columns that can hold a nonzero (skip entry checks outside it).
    int minc = c4, maxc = c4;
    if (c0 >= 0) { minc = min(minc, c0); maxc = max(maxc, c0); }
    if (c1 >= 0) { minc = min(minc, c1); maxc = max(maxc, c1); }
    if (c2 >= 0) { minc = min(minc, c2); maxc = max(maxc, c2); }
    if (c3 >= 0) { minc = min(minc, c3); maxc = max(maxc, c3); }

    // cc >= 0 always, and unused c-slots are -1, so no false matches.
    #define PICK(cc) ((cc) == c0 ? v0 : (cc) == c1 ? v1 : (cc) == c2 ? v2 : \
                      (cc) == c3 ? v3 : (cc) == c4 ? v4 : 0.0f)

    float* __restrict__ row = M + (size_t)i * (size_t)N;
    const int nvec = N >> 2;                // N=10000 -> 2500 float4 per row

    for (int v = tid; v < nvec; v += 256) {
        int c = v << 2;
        float4 out = make_float4(0.f, 0.f, 0.f, 0.f);
        if (c <= maxc && c + 3 >= minc) {   // only ~2% of vectors hit this path
            out.x = PICK(c);
            out.y = PICK(c + 1);
            out.z = PICK(c + 2);
            out.w = PICK(c + 3);
        }
        reinterpret_cast<float4*>(row)[v] = out;   // coalesced 16B/lane stream
    }
    // Tail for N % 4 != 0 (not hit at N=10000; kept for safety).
    for (int c = (nvec << 2) + tid; c < N; c += 256) {
        row[c] = PICK(c);
    }
    #undef PICK
}

extern "C" void kernel_launch(void* const* d_in, const int* in_sizes, int n_in,
                              void* d_out, int out_size, void* d_ws, size_t ws_size,
                              hipStream_t stream) {
    const float* pot      = (const float*)d_in[0];   // previous_potential [N]
    const float* chan     = (const float*)d_in[1];   // channel_size [L]
    const float* sheet    = (const float*)d_in[2];   // sheet_thickness [N]
    const float* face_len = (const float*)d_in[3];   // length_of_face [L]
    const float* link_len = (const float*)d_in[4];   // length_of_link [L]
    const int*   adj      = (const int*)d_in[5];     // adjacent_nodes [N,4]
    const int*   lnk      = (const int*)d_in[6];     // links_at_node [N,4]
    const int*   fal      = (const int*)d_in[7];     // face_at_link [L]
    const int*   head     = (const int*)d_in[8];     // link_head [L]
    const int*   tail     = (const int*)d_in[9];     // link_tail [L]
    const int*   inout    = (const int*)d_in[10];    // inflow_outflow [N]

    float* M = (float*)d_out;
    int N = in_sizes[0];                             // 10000

    // One block per row; each block writes its full row exactly once.
    sgds_row_kernel<<<N, 256, 0, stream>>>(pot, chan, sheet, face_len, link_len,
                                           adj, lnk, fal, head, tail, inout, M, N);
}

// Round 2
// 417.883 us; speedup vs baseline: 1.0039x; 1.0039x over previous
//
#include <hip/hip_runtime.h>
#include <math.h>

// Problem constants (from reference)
#define K_SHEET   0.01f
#define K_CHAN    0.1f
#define CAV_SPACE 2.0f
#define FLOW_EXP  1.25f

// DISS = (1/917 - 1/1000)/3.34e5, computed in double, used as f32 (matches jnp cast)
__device__ __constant__ float c_diss = (float)((1.0 / 917.0 - 1.0 / 1000.0) / 3.34e5);

// One block per matrix row.
//
// Phase 1: ALL 256 threads immediately stream the full row as float4 zeros —
//          the hot loop is identical in structure to rocclr's fillBuffer
//          (address + dwordx4 store, no branches, no selects, no LDS).
//          Stores are fire-and-forget, so phase 2's latency chain overlaps
//          the store drain.
// Phase 2: lanes 0..3 of wave 0 compute the per-slot terms in registers
//          (expressions copied verbatim from the verified kernel -> bit-exact).
// Phase 3: __syncthreads(). On gfx950 the compiler emits
//          s_waitcnt vmcnt(0) before s_barrier, so every zero-store in the
//          block has completed before any patch store issues.
// Phase 4: lanes 0..3 overwrite the <=4 off-diagonal entries; lane 0 writes
//          the diagonal (shfl-assembled in exact s=0..3 accumulation order).
__global__ __launch_bounds__(256)
void sgds_row_kernel(const float* __restrict__ pot,          // [N]
                     const float* __restrict__ chan,         // [L]
                     const float* __restrict__ sheet,        // [N]
                     const float* __restrict__ face_len,     // [L]
                     const float* __restrict__ link_len,     // [L]
                     const int*   __restrict__ adj,          // [N,4]
                     const int*   __restrict__ lnk,          // [N,4]
                     const int*   __restrict__ fal,          // [L]
                     const int*   __restrict__ head,         // [L]
                     const int*   __restrict__ tail,         // [L]
                     const int*   __restrict__ inout,        // [N]
                     float*       __restrict__ M,            // [N,N]
                     int N)
{
    const int i   = blockIdx.x;        // row id (uniform)
    const int tid = threadIdx.x;

    float* __restrict__ row = M + (size_t)i * (size_t)N;

    // ---- Phase 1: pure streaming zero-fill of the row (all threads) ----
    const int nvec = N >> 2;                 // N=10000 -> 2500 float4
    const float4 z = make_float4(0.f, 0.f, 0.f, 0.f);
    for (int v = tid; v < nvec; v += 256) {
        reinterpret_cast<float4*>(row)[v] = z;       // coalesced 16B/lane
    }
    for (int c = (nvec << 2) + tid; c < N; c += 256) // tail (not hit at N=10000)
        row[c] = 0.f;

    // ---- Phase 2: term computation, lanes 0..3 of wave 0, registers only ----
    float term = 0.0f;          // absent slot contributes +0.0f to diag (bit-transparent)
    int   col  = -1;
    bool  dirichlet = false;

    if (tid < 4) {
        dirichlet = (inout[i] == 1);
        if (!dirichlet) {
            const int s = tid;
            int j = adj[i * 4 + s];
            if (j >= 0) {
                int   lid = lnk[i * 4 + s];
                int   h   = head[lid];
                int   t   = tail[lid];
                float ll  = link_len[lid];
                float g   = (pot[h] - pot[t]) / ll;                 // grad[lid]

                float cq  = -K_CHAN * powf(chan[lid], FLOW_EXP) * g;          // chan_q
                float stl = 0.5f * (sheet[h] + sheet[t]);
                float ginv_sqrt = 1.0f / sqrtf(fabsf(g));                      // |g|^-0.5
                float sq  = -K_SHEET * powf(stl, FLOW_EXP) * ginv_sqrt * g;    // sheet_q

                float fl = face_len[fal[lid]];
                // NOTE: reference indexes channel_size (link field) by NODE ids — kept.
                float cs = 0.5f * (chan[i] + chan[j]);
                float st = 0.5f * (sheet[i] + sheet[j]);

                float sheet_flux = -K_SHEET * powf(st, FLOW_EXP) * ginv_sqrt * fl / ll;
                float chan_flux  = -K_CHAN  * powf(cs, FLOW_EXP) * fl / ll;
                float ch_diss    = fabsf(c_diss * cq * fl);
                float sh_diss    = fabsf(c_diss * sq * CAV_SPACE * fl);

                term = sheet_flux + chan_flux + ch_diss + sh_diss;
                col  = j;
            }
        }
    }

    // ---- Phase 3: order zero-stores before patch-stores ----
    __syncthreads();   // emits s_waitcnt vmcnt(0) + s_barrier on gfx950

    // ---- Phase 4: patch the <=5 nonzeros ----
    if (tid < 4) {
        if (dirichlet) {
            if (tid == 0) row[i] = 1.0f;                 // identity row
        } else {
            // diag in exact s=0..3 accumulation order (absent slots are +0.0f)
            float t0 = __shfl(term, 0);
            float t1 = __shfl(term, 1);
            float t2 = __shfl(term, 2);
            float t3 = __shfl(term, 3);
            if (col >= 0) row[col] = -term;              // off-diagonal
            if (tid == 0) row[i] = ((t0 + t1) + t2) + t3; // diagonal
        }
    }
}

extern "C" void kernel_launch(void* const* d_in, const int* in_sizes, int n_in,
                              void* d_out, int out_size, void* d_ws, size_t ws_size,
                              hipStream_t stream) {
    const float* pot      = (const float*)d_in[0];   // previous_potential [N]
    const float* chan     = (const float*)d_in[1];   // channel_size [L]
    const float* sheet    = (const float*)d_in[2];   // sheet_thickness [N]
    const float* face_len = (const float*)d_in[3];   // length_of_face [L]
    const float* link_len = (const float*)d_in[4];   // length_of_link [L]
    const int*   adj      = (const int*)d_in[5];     // adjacent_nodes [N,4]
    const int*   lnk      = (const int*)d_in[6];     // links_at_node [N,4]
    const int*   fal      = (const int*)d_in[7];     // face_at_link [L]
    const int*   head     = (const int*)d_in[8];     // link_head [L]
    const int*   tail     = (const int*)d_in[9];     // link_tail [L]
    const int*   inout    = (const int*)d_in[10];    // inflow_outflow [N]

    float* M = (float*)d_out;
    int N = in_sizes[0];                             // 10000

    // One block per row; each block writes its full row exactly once.
    sgds_row_kernel<<<N, 256, 0, stream>>>(pot, chan, sheet, face_len, link_len,
                                           adj, lnk, fal, head, tail, inout, M, N);
}